// Round 8
// baseline (448.895 us; speedup 1.0000x reference)
//
#include <hip/hip_runtime.h>
#include <cstddef>

#define NNODES 40000
#define NEDGES 640000
#define NETOT  (NNODES + NEDGES)
#define ELLW   96          // fixed edge slots per node; overflow -> spill list

typedef unsigned short u16;
typedef unsigned int   u32;
using v2f = __attribute__((ext_vector_type(2))) float;

// ---------------- helpers ----------------
__device__ inline float wave_sum(float v) {
#pragma unroll
    for (int o = 32; o > 0; o >>= 1) v += __shfl_xor(v, o);
    return v;
}
__device__ inline u16 f2bf(float f) {   // round-to-nearest-even f32 -> bf16
    u32 u = __float_as_uint(f);
    return (u16)((u + 0x7fffu + ((u >> 16) & 1u)) >> 16);
}

// ---------------- ELL build (cnt pre-zeroed by prep_kernel; spill count = cnt[N]) ----------------
__global__ void ell_scatter_kernel(const int* __restrict__ ei, int* __restrict__ cnt,
                                   int* __restrict__ srcs, int2* __restrict__ ovbuf) {
    int idx = blockIdx.x * blockDim.x + threadIdx.x;
    if (idx >= NETOT) return;
    int src, dst;
    if (idx < NEDGES) { src = ei[idx]; dst = ei[NEDGES + idx]; }
    else              { src = idx - NEDGES; dst = src; }
    int p = atomicAdd(&cnt[dst], 1);
    if (p < ELLW) srcs[dst * ELLW + p] = src;
    else {
        int q = atomicAdd(&cnt[NNODES], 1);   // spill (capacity NETOT: never drops)
        ovbuf[q] = make_int2(dst, src);
    }
}

// ---------------- prep: zero cnt[N+1] + cast 6 weight matrices (float4 groups) ----------------
__global__ void prep_kernel(int* __restrict__ cnt,
                            const float* s0, u16* d0, int n0, const float* s1, u16* d1, int n1,
                            const float* s2, u16* d2, int n2, const float* s3, u16* d3, int n3,
                            const float* s4, u16* d4, int n4, const float* s5, u16* d5, int n5) {
    int i = blockIdx.x * blockDim.x + threadIdx.x;
    if (i <= NNODES) cnt[i] = 0;
    i -= (NNODES + 1);
    if (i < 0) return;
    const float* s; u16* d;
    if      (i < n0) { s = s0; d = d0; }
    else if ((i -= n0) < n1) { s = s1; d = d1; }
    else if ((i -= n1) < n2) { s = s2; d = d2; }
    else if ((i -= n2) < n3) { s = s3; d = d3; }
    else if ((i -= n3) < n4) { s = s4; d = d4; }
    else if ((i -= n4) < n5) { s = s5; d = d5; }
    else return;
    float4 v = ((const float4*)s)[i];
    ushort4 o; o.x = f2bf(v.x); o.y = f2bf(v.y); o.z = f2bf(v.z); o.w = f2bf(v.w);
    ((ushort4*)d)[i] = o;
}

// ---------------- GEMM (128-wide N tile) + fused attention scores ----------------
template <int H, int C, bool AF32>
__global__ void gemm_scores_kernel(const void* __restrict__ Aptr, const u16* __restrict__ B,
                                   u16* __restrict__ Cout,
                                   const float* __restrict__ as, const float* __restrict__ ad,
                                   float* __restrict__ es, float* __restrict__ ed,
                                   int M, int Nn, int K) {
    constexpr int HT = 128 / C;
    using bfrag = __attribute__((ext_vector_type(8))) short;
    using ffrag = __attribute__((ext_vector_type(4))) float;
    int wave = threadIdx.x >> 6, lane = threadIdx.x & 63;
    int lm = lane & 15, kg = (lane >> 4) * 8;
    int rowblk = blockIdx.x * 64 + wave * 16;
    int n0 = blockIdx.y * 128;
    const u16* Bp = B + (size_t)(n0 + lm) * K + kg;
    ffrag acc[8] = {};
    for (int k0 = 0; k0 < K; k0 += 32) {
        bfrag af;
        if constexpr (AF32) {
            const float* ap = (const float*)Aptr + (size_t)(rowblk + lm) * K + kg + k0;
            float4 a0 = *(const float4*)ap;
            float4 a1 = *(const float4*)(ap + 4);
            af[0] = (short)f2bf(a0.x); af[1] = (short)f2bf(a0.y);
            af[2] = (short)f2bf(a0.z); af[3] = (short)f2bf(a0.w);
            af[4] = (short)f2bf(a1.x); af[5] = (short)f2bf(a1.y);
            af[6] = (short)f2bf(a1.z); af[7] = (short)f2bf(a1.w);
        } else {
            af = *(const bfrag*)((const u16*)Aptr + (size_t)(rowblk + lm) * K + kg + k0);
        }
#pragma unroll
        for (int t = 0; t < 8; t++) {
            bfrag bf = *(const bfrag*)(Bp + (size_t)t * 16 * K + k0);
            acc[t] = __builtin_amdgcn_mfma_f32_16x16x32_bf16(af, bf, acc[t], 0, 0, 0);
        }
    }
    int orow = rowblk + (lane >> 4) * 4;   // C/D: col = lane&15, row = (lane>>4)*4 + reg
    float asv[8], adv[8];
#pragma unroll
    for (int t = 0; t < 8; t++) {
        int fcol = n0 + t * 16 + lm;
        asv[t] = as[fcol]; adv[t] = ad[fcol];
    }
    float ps[4][HT] = {}, pd[4][HT] = {};
#pragma unroll
    for (int t = 0; t < 8; t++) {
        const int hh = t / (C / 16);
#pragma unroll
        for (int r = 0; r < 4; r++) {
            float v = acc[t][r];
            ps[r][hh] += v * asv[t];
            pd[r][hh] += v * adv[t];
            Cout[(size_t)(orow + r) * Nn + n0 + t * 16 + lm] = f2bf(v);
        }
    }
    int hb = blockIdx.y * HT;
#pragma unroll
    for (int r = 0; r < 4; r++)
#pragma unroll
        for (int hh = 0; hh < HT; hh++) {
            float s = ps[r][hh], d = pd[r][hh];
#pragma unroll
            for (int o = 1; o < 16; o <<= 1) { s += __shfl_xor(s, o); d += __shfl_xor(d, o); }
            if (lm == 0) {
                es[(size_t)(orow + r) * H + hb + hh] = s;
                ed[(size_t)(orow + r) * H + hb + hh] = d;
            }
        }
}

// ---------------- fused GAT softmax + aggregation: 2 waves per node ----------------
// Block = 4 waves = 2 nodes. Phase 1: slots 0-63 (subwave0) / 64-95 (subwave1) in one
// pass; raw weights staged in LDS; denominators merged via LDS. Phase 2: 8-edge groups
// split alternately between the node's two waves (serial chain halved); partials merged
// via LDS; single final scale y = acc*inv + bias (normalization folded out of the loop).
template <int H, int C, bool LNRELU>
__global__ void gat_fused_kernel(const u16* __restrict__ hmat,
                                 const float* __restrict__ es, const float* __restrict__ ed,
                                 const int* __restrict__ cnt, const int* __restrict__ srcs,
                                 const int2* __restrict__ ovbuf,
                                 const float* __restrict__ bias,
                                 const float* __restrict__ lng, const float* __restrict__ lnb,
                                 void* __restrict__ out, int n) {
    constexpr int HC = H * C;
    constexpr int VPT = HC / 64;
    constexpr int SH = (HC == 256) ? 9 : 8;      // byte-offset shift for h rows
    __shared__ float wbuf[2][H][100];
    __shared__ int   sbuf[2][ELLW];
    __shared__ float denp[2][2][H];
    __shared__ float pbuf[2][64][VPT];
    int wave = threadIdx.x >> 6, lane = threadIdx.x & 63;
    int nl = wave >> 1, sw = wave & 1;
    int wid = blockIdx.x * 2 + nl;               // n is even; always alive

    int degt = cnt[wid];
    int mainc = degt < ELLW ? degt : ELLW;
    int base = wid * ELLW;

    float edi[H];
#pragma unroll
    for (int hh = 0; hh < H; hh++) edi[hh] = ed[(size_t)wid * H + hh];

    // ---- phase 1: weights for slot i = sw*64+lane (single pass; ELLW<=128) ----
    float den[H];
#pragma unroll
    for (int hh = 0; hh < H; hh++) den[hh] = 0.f;
    {
        int i = sw * 64 + lane;
        if (i < mainc) {
            int s = srcs[base + i];
            sbuf[nl][i] = s << SH;
            float ev[H];
            if constexpr (H == 4) { float4 t = ((const float4*)es)[s]; ev[0]=t.x; ev[1]=t.y; ev[2]=t.z; ev[3]=t.w; }
            else if constexpr (H == 2) { float2 t = ((const float2*)es)[s]; ev[0]=t.x; ev[1]=t.y; }
            else { ev[0] = es[s]; }
#pragma unroll
            for (int hh = 0; hh < H; hh++) {
                float v = ev[hh] + edi[hh];
                v = v > 0.f ? v : 0.2f * v;
                float w = __expf(v);
                den[hh] = w;
                wbuf[nl][hh][i] = w;
            }
        }
    }
    int ovn = 0;
    if (degt > ELLW) {                            // rare spill: denominator part
        ovn = cnt[n];
        for (int j = sw * 64 + lane; j < ovn; j += 128) {
            int2 t = ovbuf[j];
            if (t.x == wid) {
#pragma unroll
                for (int hh = 0; hh < H; hh++) {
                    float v = es[(size_t)t.y * H + hh] + edi[hh];
                    v = v > 0.f ? v : 0.2f * v;
                    den[hh] += __expf(v);
                }
            }
        }
    }
#pragma unroll
    for (int hh = 0; hh < H; hh++) {
        float s = wave_sum(den[hh]);
        if (lane == 0) denp[nl][sw][hh] = s;
    }
    __syncthreads();

    // ---- phase 2: this wave takes 8-edge groups g == sw (mod 2) ----
    const int myhead = (lane * VPT) / C;
    const float invh = 1.f / (denp[nl][0][myhead] + denp[nl][1][myhead] + 1e-16f);
    const int loff = lane * (VPT * 2);
    v2f a01 = {0.f, 0.f}, a23 = {0.f, 0.f};

    int ng = mainc >> 3;
    for (int g = sw; g < ng; g += 2) {
        int e = g * 8;
        int4   o0 = *(const int4*)&sbuf[nl][e];
        int4   o1 = *(const int4*)&sbuf[nl][e + 4];
        float4 w0 = *(const float4*)&wbuf[nl][myhead][e];
        float4 w1 = *(const float4*)&wbuf[nl][myhead][e + 4];
        int   oo[8] = {o0.x, o0.y, o0.z, o0.w, o1.x, o1.y, o1.z, o1.w};
        float ww[8] = {w0.x, w0.y, w0.z, w0.w, w1.x, w1.y, w1.z, w1.w};
        if constexpr (VPT == 4) {
            uint2 gg[8];
#pragma unroll
            for (int u = 0; u < 8; u++)
                gg[u] = *(const uint2*)((const char*)hmat + (size_t)(u32)oo[u] + loff);
#pragma unroll
            for (int u = 0; u < 8; u++) {
                v2f wv = {ww[u], ww[u]};
                v2f h01, h23;
                h01.x = __uint_as_float(gg[u].x << 16);
                h01.y = __uint_as_float(gg[u].x & 0xffff0000u);
                h23.x = __uint_as_float(gg[u].y << 16);
                h23.y = __uint_as_float(gg[u].y & 0xffff0000u);
                a01 += wv * h01;
                a23 += wv * h23;
            }
        } else {
            u32 gg[8];
#pragma unroll
            for (int u = 0; u < 8; u++)
                gg[u] = *(const u32*)((const char*)hmat + (size_t)(u32)oo[u] + loff);
#pragma unroll
            for (int u = 0; u < 8; u++) {
                v2f wv = {ww[u], ww[u]};
                v2f h01;
                h01.x = __uint_as_float(gg[u] << 16);
                h01.y = __uint_as_float(gg[u] & 0xffff0000u);
                a01 += wv * h01;
            }
        }
    }
    int full = ng * 8;
    if (sw == (ng & 1)) {                         // tail edges
        for (int e = full; e < mainc; e++) {
            int off = sbuf[nl][e];
            float w = wbuf[nl][myhead][e];
            v2f wv = {w, w};
            if constexpr (VPT == 4) {
                uint2 g = *(const uint2*)((const char*)hmat + (size_t)(u32)off + loff);
                v2f h01, h23;
                h01.x = __uint_as_float(g.x << 16);
                h01.y = __uint_as_float(g.x & 0xffff0000u);
                h23.x = __uint_as_float(g.y << 16);
                h23.y = __uint_as_float(g.y & 0xffff0000u);
                a01 += wv * h01;
                a23 += wv * h23;
            } else {
                u32 g = *(const u32*)((const char*)hmat + (size_t)(u32)off + loff);
                v2f h01;
                h01.x = __uint_as_float(g << 16);
                h01.y = __uint_as_float(g & 0xffff0000u);
                a01 += wv * h01;
            }
        }
    }
    if (sw == 0 && degt > ELLW) {                 // rare spill accumulate (raw weights)
        const float edh = edi[myhead];
        for (int j = 0; j < ovn; j++) {
            int2 t = ovbuf[j];
            if (t.x != wid) continue;
            float v = es[(size_t)t.y * H + myhead] + edh;
            v = v > 0.f ? v : 0.2f * v;
            float w = __expf(v);
            v2f wv = {w, w};
            if constexpr (VPT == 4) {
                uint2 g = *(const uint2*)((const char*)hmat + ((size_t)t.y << SH) + loff);
                v2f h01, h23;
                h01.x = __uint_as_float(g.x << 16);
                h01.y = __uint_as_float(g.x & 0xffff0000u);
                h23.x = __uint_as_float(g.y << 16);
                h23.y = __uint_as_float(g.y & 0xffff0000u);
                a01 += wv * h01;
                a23 += wv * h23;
            } else {
                u32 g = *(const u32*)((const char*)hmat + ((size_t)t.y << SH) + loff);
                v2f h01;
                h01.x = __uint_as_float(g << 16);
                h01.y = __uint_as_float(g & 0xffff0000u);
                a01 += wv * h01;
            }
        }
    }

    // ---- merge subwave partials ----
    if (sw == 1) {
        pbuf[nl][lane][0] = a01.x;
        pbuf[nl][lane][1] = a01.y;
        if constexpr (VPT == 4) { pbuf[nl][lane][2] = a23.x; pbuf[nl][lane][3] = a23.y; }
    }
    __syncthreads();
    if (sw == 1) return;

    int fbase = lane * VPT;
    float y[VPT];
    y[0] = (a01.x + pbuf[nl][lane][0]) * invh + bias[fbase + 0];
    y[1] = (a01.y + pbuf[nl][lane][1]) * invh + bias[fbase + 1];
    if constexpr (VPT == 4) {
        y[2] = (a23.x + pbuf[nl][lane][2]) * invh + bias[fbase + 2];
        y[3] = (a23.y + pbuf[nl][lane][3]) * invh + bias[fbase + 3];
    }

    if constexpr (LNRELU) {
        float s1 = 0.f, s2 = 0.f;
#pragma unroll
        for (int j = 0; j < VPT; j++) { s1 += y[j]; s2 += y[j] * y[j]; }
        s1 = wave_sum(s1);
        s2 = wave_sum(s2);
        float mu = s1 / (float)HC;
        float var = s2 / (float)HC - mu * mu;
        float rstd = rsqrtf(var + 1e-5f);
#pragma unroll
        for (int j = 0; j < VPT; j++) {
            float v = (y[j] - mu) * rstd * lng[fbase + j] + lnb[fbase + j];
            y[j] = v > 0.f ? v : 0.f;
        }
        u16* op = (u16*)out + (size_t)wid * HC + fbase;
        if constexpr (VPT == 4) {
            ushort4 o; o.x = f2bf(y[0]); o.y = f2bf(y[1]); o.z = f2bf(y[2]); o.w = f2bf(y[3]);
            *(ushort4*)op = o;
        } else {
            ushort2 o; o.x = f2bf(y[0]); o.y = f2bf(y[1]);
            *(ushort2*)op = o;
        }
    } else {
        float* op = (float*)out + (size_t)wid * HC + fbase;
        if constexpr (VPT == 4) *(float4*)op = make_float4(y[0], y[1], y[2], y[3]);
        else                    *(float2*)op = make_float2(y[0], y[1]);
    }
}

// ---------------- PointNet layers 1+2 fused ----------------
__global__ void gemm_pn12_kernel(const float* __restrict__ pos,
                                 const float* __restrict__ pw1, const float* __restrict__ pb1,
                                 const float* __restrict__ bn1g, const float* __restrict__ bn1b,
                                 const u16* __restrict__ B, u16* __restrict__ Cout,
                                 const float* __restrict__ pb2,
                                 const float* __restrict__ bn2g, const float* __restrict__ bn2b,
                                 int M) {
    const int Nn = 128, K = 64;
    using bfrag = __attribute__((ext_vector_type(8))) short;
    using ffrag = __attribute__((ext_vector_type(4))) float;
    int wave = threadIdx.x >> 6, lane = threadIdx.x & 63;
    int lm = lane & 15, kg = (lane >> 4) * 8;
    int rowblk = blockIdx.x * 64 + wave * 16;
    int row = rowblk + lm;
    float p0 = pos[row * 3 + 0], p1 = pos[row * 3 + 1], p2 = pos[row * 3 + 2];
    const u16* Bp = B + (size_t)lm * K + kg;
    const float bnscale = rsqrtf(1.0f + 1e-5f);
    ffrag acc[8] = {};
#pragma unroll
    for (int k0 = 0; k0 < K; k0 += 32) {
        bfrag af;
#pragma unroll
        for (int j = 0; j < 8; j++) {
            int k = kg + k0 + j;
            float v = p0 * pw1[k * 3 + 0] + p1 * pw1[k * 3 + 1] + p2 * pw1[k * 3 + 2] + pb1[k];
            v = v * (bn1g[k] * bnscale) + bn1b[k];
            v = v > 0.f ? v : 0.f;
            af[j] = (short)f2bf(v);
        }
#pragma unroll
        for (int t = 0; t < 8; t++) {
            bfrag bf = *(const bfrag*)(Bp + (size_t)t * 16 * K + k0);
            acc[t] = __builtin_amdgcn_mfma_f32_16x16x32_bf16(af, bf, acc[t], 0, 0, 0);
        }
    }
    int orow = rowblk + (lane >> 4) * 4;
#pragma unroll
    for (int t = 0; t < 8; t++) {
        int col = t * 16 + lm;
        float bi = pb2[col], g = bn2g[col] * bnscale, bb = bn2b[col];
#pragma unroll
        for (int r = 0; r < 4; r++) {
            float v = (acc[t][r] + bi) * g + bb;
            v = v > 0.f ? v : 0.f;
            Cout[(size_t)(orow + r) * Nn + col] = f2bf(v);
        }
    }
}

// ---------------- fused: pf = p2@pw3^T + pb3; out = [x3|pf]@fw^T + fb ----------------
__global__ void gemm_pw3cat_kernel(const u16* __restrict__ p2, const u16* __restrict__ Bpw3,
                                   const float* __restrict__ pb3, float* __restrict__ pf,
                                   const float* __restrict__ x3, const u16* __restrict__ Bfw,
                                   const float* __restrict__ fb, float* __restrict__ outp,
                                   int M) {
    using bfrag = __attribute__((ext_vector_type(8))) short;
    using ffrag = __attribute__((ext_vector_type(4))) float;
    __shared__ float pft[64][132];
    int wave = threadIdx.x >> 6, lane = threadIdx.x & 63;
    int lm = lane & 15, kg = (lane >> 4) * 8;
    int rowblk = blockIdx.x * 64 + wave * 16;

    {   // ---- stage 1: pf tile (K=128, Nn=128) ----
        const u16* Ap = p2 + (size_t)(rowblk + lm) * 128 + kg;
        const u16* Bp = Bpw3 + (size_t)lm * 128 + kg;
        ffrag acc[8] = {};
#pragma unroll
        for (int k0 = 0; k0 < 128; k0 += 32) {
            bfrag af = *(const bfrag*)(Ap + k0);
#pragma unroll
            for (int t = 0; t < 8; t++) {
                bfrag bf = *(const bfrag*)(Bp + (size_t)t * 16 * 128 + k0);
                acc[t] = __builtin_amdgcn_mfma_f32_16x16x32_bf16(af, bf, acc[t], 0, 0, 0);
            }
        }
        int orow = rowblk + (lane >> 4) * 4;
        int lrow = wave * 16 + (lane >> 4) * 4;
#pragma unroll
        for (int t = 0; t < 8; t++) {
            int col = t * 16 + lm;
            float bi = pb3[col];
#pragma unroll
            for (int r = 0; r < 4; r++) {
                float v = acc[t][r] + bi;
                pf[(size_t)(orow + r) * 128 + col] = v;
                pft[lrow + r][col] = v;
            }
        }
    }
    __syncthreads();

    {   // ---- stage 2: out = [x3|pf]@fw^T + fb (K=256, Nn=128) ----
        const u16* Bp = Bfw + (size_t)lm * 256 + kg;
        ffrag acc[8] = {};
        int row = rowblk + lm, lrow = wave * 16 + lm;
#pragma unroll
        for (int k0 = 0; k0 < 256; k0 += 32) {
            bfrag af;
            const float* ap = (k0 < 128) ? (x3 + (size_t)row * 128 + kg + k0)
                                         : (&pft[lrow][kg + k0 - 128]);
            float4 a0 = *(const float4*)ap;
            float4 a1 = *(const float4*)(ap + 4);
            af[0] = (short)f2bf(a0.x); af[1] = (short)f2bf(a0.y);
            af[2] = (short)f2bf(a0.z); af[3] = (short)f2bf(a0.w);
            af[4] = (short)f2bf(a1.x); af[5] = (short)f2bf(a1.y);
            af[6] = (short)f2bf(a1.z); af[7] = (short)f2bf(a1.w);
#pragma unroll
            for (int t = 0; t < 8; t++) {
                bfrag bf = *(const bfrag*)(Bp + (size_t)t * 16 * 256 + k0);
                acc[t] = __builtin_amdgcn_mfma_f32_16x16x32_bf16(af, bf, acc[t], 0, 0, 0);
            }
        }
        int orow = rowblk + (lane >> 4) * 4;
#pragma unroll
        for (int t = 0; t < 8; t++) {
            int col = t * 16 + lm;
            float bi = fb[col];
#pragma unroll
            for (int r = 0; r < 4; r++)
                outp[(size_t)(orow + r) * 128 + col] = acc[t][r] + bi;
        }
    }
}

extern "C" void kernel_launch(void* const* d_in, const int* in_sizes, int n_in,
                              void* d_out, int out_size, void* d_ws, size_t ws_size,
                              hipStream_t stream) {
    const float* x    = (const float*)d_in[0];
    const int*   ei   = (const int*)d_in[1];
    const float* pos  = (const float*)d_in[2];
    const float* W1   = (const float*)d_in[3];
    const float* as1  = (const float*)d_in[4];
    const float* ad1  = (const float*)d_in[5];
    const float* bg1  = (const float*)d_in[6];
    const float* ln1g = (const float*)d_in[7];
    const float* ln1b = (const float*)d_in[8];
    const float* W2   = (const float*)d_in[9];
    const float* as2  = (const float*)d_in[10];
    const float* ad2  = (const float*)d_in[11];
    const float* bg2  = (const float*)d_in[12];
    const float* ln2g = (const float*)d_in[13];
    const float* ln2b = (const float*)d_in[14];
    const float* W3   = (const float*)d_in[15];
    const float* as3  = (const float*)d_in[16];
    const float* ad3  = (const float*)d_in[17];
    const float* bg3  = (const float*)d_in[18];
    const float* pw1  = (const float*)d_in[19];
    const float* pb1  = (const float*)d_in[20];
    const float* bn1g = (const float*)d_in[21];
    const float* bn1b = (const float*)d_in[22];
    const float* pw2  = (const float*)d_in[23];
    const float* pb2  = (const float*)d_in[24];
    const float* bn2g = (const float*)d_in[25];
    const float* bn2b = (const float*)d_in[26];
    const float* pw3  = (const float*)d_in[27];
    const float* pb3  = (const float*)d_in[28];
    const float* fw   = (const float*)d_in[29];
    const float* fb   = (const float*)d_in[30];

    const int N = NNODES;
    float* out = (float*)d_out;                    // [N,128]
    float* x3  = out + (size_t)N * 128;            // [N,128]
    float* pf  = out + (size_t)2 * N * 128;        // [N,128]

    char* ws = (char*)d_ws;
    size_t off = 0;
    auto alloc = [&](size_t bytes) -> void* {
        void* p = ws + off;
        off += (bytes + 255) / 256 * 256;
        return p;
    };
    int*   cnt    = (int*)alloc((size_t)(N + 1) * 4);
    int*   srcs   = (int*)alloc((size_t)N * ELLW * 4);
    int2*  ovbuf  = (int2*)alloc((size_t)NETOT * 8);
    float* esb    = (float*)alloc((size_t)N * 4 * 4);
    float* edb    = (float*)alloc((size_t)N * 4 * 4);
    u16*   w1c    = (u16*)alloc(16384 * 2);
    u16*   w2c    = (u16*)alloc(32768 * 2);
    u16*   w3c    = (u16*)alloc(16384 * 2);
    u16*   pw2c   = (u16*)alloc(8192 * 2);
    u16*   pw3c   = (u16*)alloc(16384 * 2);
    u16*   fwc    = (u16*)alloc(32768 * 2);
    u16*   hbufb  = (u16*)alloc((size_t)N * 256 * 2);
    u16*   xb     = (u16*)alloc((size_t)N * 256 * 2);
    u16*   p2b    = (u16*)alloc((size_t)N * 128 * 2);

    // ---- prep (zero cnt + cast weights), then ELL build ----
    prep_kernel<<<(NNODES + 1 + 30720 + 255) / 256, 256, 0, stream>>>(
        cnt, W1, w1c, 4096, W2, w2c, 8192, W3, w3c, 4096,
        pw2, pw2c, 2048, pw3, pw3c, 4096, fw, fwc, 8192);
    ell_scatter_kernel<<<(NETOT + 255) / 256, 256, 0, stream>>>(ei, cnt, srcs, ovbuf);

    const int NW2 = N / 2;  // 2 waves per node, 2 nodes per block
    const int GB = N / 64;  // 625 GEMM row-blocks

    // ---- PointNet layers 1+2 (fused) ----
    gemm_pn12_kernel<<<GB, 256, 0, stream>>>(
        pos, pw1, pb1, bn1g, bn1b, pw2c, p2b, pb2, bn2g, bn2b, N);

    // ---- GAT layer 1 ----
    gemm_scores_kernel<4, 64, true><<<dim3(GB, 2), 256, 0, stream>>>(
        x, w1c, hbufb, as1, ad1, esb, edb, N, 256, 64);
    gat_fused_kernel<4, 64, true><<<NW2, 256, 0, stream>>>(
        hbufb, esb, edb, cnt, srcs, ovbuf, bg1, ln1g, ln1b, xb, N);

    // ---- GAT layer 2 ----
    gemm_scores_kernel<2, 64, false><<<dim3(GB, 1), 256, 0, stream>>>(
        xb, w2c, hbufb, as2, ad2, esb, edb, N, 128, 256);
    gat_fused_kernel<2, 64, true><<<NW2, 256, 0, stream>>>(
        hbufb, esb, edb, cnt, srcs, ovbuf, bg2, ln2g, ln2b, xb, N);

    // ---- GAT layer 3 (out f32 -> x3) ----
    gemm_scores_kernel<1, 128, false><<<dim3(GB, 1), 256, 0, stream>>>(
        xb, w3c, hbufb, as3, ad3, esb, edb, N, 128, 128);
    gat_fused_kernel<1, 128, false><<<NW2, 256, 0, stream>>>(
        hbufb, esb, edb, cnt, srcs, ovbuf, bg3, nullptr, nullptr, x3, N);

    // ---- pw3 GEMM + fusion GEMM (fused; writes pf and out) ----
    gemm_pw3cat_kernel<<<GB, 256, 0, stream>>>(p2b, pw3c, pb3, pf, x3, fwc, fb, out, N);
}